// Round 6
// baseline (143.338 us; speedup 1.0000x reference)
//
#include <hip/hip_runtime.h>

#define DEV __device__ __forceinline__

typedef __attribute__((ext_vector_type(8))) short bf16x8;
typedef __attribute__((ext_vector_type(4))) float f32x4;

static constexpr int NTH = 512;
static constexpr int TBE = 16;

// d_ws layout (bf16-element offsets) -- monolith/common section
static constexpr int W1P = 0;        // [128][32]  swz3 (K padded 16->32)
static constexpr int W2  = 4096;     // [128][128] swz7
static constexpr int WQ  = 20480;
static constexpr int WK  = 36864;
static constexpr int WVW = 53248;
static constexpr int OW  = 69632;
static constexpr int P1A = 86016;
static constexpr int P1B = 102400;
static constexpr int P2W = 118784;
static constexpr int WS_BF16_TOT = 135168;   // wsp (f32) follows, 2304 floats
static constexpr int NPRM = 18 * 128;
// split-path extras (bf16-element offsets)
static constexpr int WQr  = 139776;  // row-major bf16 copies
static constexpr int OWr  = 156160;
static constexpr int P1Ar = 172544;
static constexpr int P1Br = 188928;
static constexpr int P2r  = 205312;
static constexpr int WKt  = 221696;  // Wk TRANSPOSED [c'][j] for qk_h = Wk_h^T q_h
static constexpr int CURE = 238080;               // cur_emb [32768][128]
static constexpr int NBE  = 238080 + 4194304;     // nb_emb  [262144][128]
static constexpr size_t SPLIT_NEED = (size_t)(NBE + 33554432) * 2;  // ~76.0 MB
// param slots: 0 b1,1 g1,2 be1,3 b2,4 g2,5 be2,6 bq,7 bk,8 bv,9 out_b,
//              10 an_g,11 an_b,12 p1_b,13 p1_g,14 p1_be,15 p2_b,16 p2_g,17 p2_be

DEV unsigned short f2bf(float f) {
  unsigned u = __float_as_uint(f);
  return (unsigned short)((u + 0x7fffu + ((u >> 16) & 1u)) >> 16);
}
DEV float bf2f(unsigned short u) { return __uint_as_float(((unsigned)u) << 16); }

DEV void st_bf16(unsigned short* buf, int row, int col, float v) {
  buf[row * 128 + ((((col >> 3) ^ (row & 7)) << 3) | (col & 7))] = f2bf(v);
}
DEV float ld_bf16(const unsigned short* buf, int row, int col) {
  unsigned u = buf[row * 128 + ((((col >> 3) ^ (row & 7)) << 3) | (col & 7))];
  return __uint_as_float(u << 16);
}
DEV bf16x8 frag128(const unsigned short* buf, int row, int kk, int lg) {
  return *(const bf16x8*)(buf + row * 128 + (((kk * 4 + lg) ^ (row & 7)) << 3));
}
DEV bf16x8 frag32(const unsigned short* buf, int row, int lg) {
  return *(const bf16x8*)(buf + row * 32 + ((lg ^ (row & 3)) << 3));
}
DEV f32x4 mfma16(bf16x8 a, bf16x8 b, f32x4 c) {
  return __builtin_amdgcn_mfma_f32_16x16x32_bf16(a, b, c, 0, 0, 0);
}

// ---------------- prep: weights -> d_ws (swizzled + row-major + params) ----------------
__global__ void prep(const float* __restrict__ enc_w1, const float* __restrict__ enc_w2,
                     const float* __restrict__ in_pw, const float* __restrict__ out_w,
                     const float* __restrict__ p1_w, const float* __restrict__ p2_w,
                     const float* __restrict__ enc_b1, const float* __restrict__ enc_g1,
                     const float* __restrict__ enc_be1, const float* __restrict__ enc_b2,
                     const float* __restrict__ enc_g2, const float* __restrict__ enc_be2,
                     const float* __restrict__ in_pb, const float* __restrict__ out_b,
                     const float* __restrict__ an_g, const float* __restrict__ an_b,
                     const float* __restrict__ p1_b, const float* __restrict__ p1_g,
                     const float* __restrict__ p1_be, const float* __restrict__ p2_b,
                     const float* __restrict__ p2_g, const float* __restrict__ p2_be,
                     unsigned short* __restrict__ wsb, float* __restrict__ wsp, int rm) {
  int t = blockIdx.x * blockDim.x + threadIdx.x;
  int NT = gridDim.x * blockDim.x;
  for (int i = t; i < 8 * 16384; i += NT) {
    int mi = i >> 14, e = i & 16383, row = e >> 7, col = e & 127;
    float v; int dstb;
    switch (mi) {
      case 0: v = enc_w2[row * 128 + col];         dstb = W2;  break;
      case 1: v = in_pw[row * 128 + col];          dstb = WQ;  break;
      case 2: v = in_pw[(128 + row) * 128 + col];  dstb = WK;  break;
      case 3: v = in_pw[(256 + row) * 128 + col];  dstb = WVW; break;
      case 4: v = out_w[row * 128 + col];          dstb = OW;  break;
      case 5: v = p1_w[row * 256 + col];           dstb = P1A; break;
      case 6: v = p1_w[row * 256 + 128 + col];     dstb = P1B; break;
      default: v = p2_w[row * 128 + col];          dstb = P2W; break;
    }
    wsb[dstb + row * 128 + ((((col >> 3) ^ (row & 7)) << 3) | (col & 7))] = f2bf(v);
  }
  for (int i = t; i < 4096; i += NT) {
    int row = i >> 5, col = i & 31;
    float v = (col < 16) ? enc_w1[row * 16 + col] : 0.f;
    wsb[W1P + row * 32 + ((((col >> 3) ^ (row & 3)) << 3) | (col & 7))] = f2bf(v);
  }
  if (rm) {  // row-major bf16 copies (+ Wk^T) for split-path direct global fragment reads
    for (int i = t; i < 6 * 16384; i += NT) {
      int mi = i >> 14, e = i & 16383, row = e >> 7, col = e & 127;
      float v; int dstb;
      switch (mi) {
        case 0: v = in_pw[row * 128 + col];         dstb = WQr;  break;
        case 1: v = out_w[row * 128 + col];         dstb = OWr;  break;
        case 2: v = p1_w[row * 256 + col];          dstb = P1Ar; break;
        case 3: v = p1_w[row * 256 + 128 + col];    dstb = P1Br; break;
        case 4: v = p2_w[row * 128 + col];          dstb = P2r;  break;
        default: v = in_pw[(128 + col) * 128 + row]; dstb = WKt; break;  // Wk^T[c'][j]
      }
      wsb[dstb + e] = f2bf(v);
    }
  }
  for (int i = t; i < NPRM; i += NT) {
    int s = i >> 7, c = i & 127; float v;
    switch (s) {
      case 0: v = enc_b1[c]; break;  case 1: v = enc_g1[c]; break;
      case 2: v = enc_be1[c]; break; case 3: v = enc_b2[c]; break;
      case 4: v = enc_g2[c]; break;  case 5: v = enc_be2[c]; break;
      case 6: v = in_pb[c]; break;   case 7: v = in_pb[128 + c]; break;
      case 8: v = in_pb[256 + c]; break; case 9: v = out_b[c]; break;
      case 10: v = an_g[c]; break;   case 11: v = an_b[c]; break;
      case 12: v = p1_b[c]; break;   case 13: v = p1_g[c]; break;
      case 14: v = p1_be[c]; break;  case 15: v = p2_b[c]; break;
      case 16: v = p2_g[c]; break;   default: v = p2_be[c]; break;
    }
    wsp[i] = v;
  }
}

// ================= K1: encoder (coalesced I/O via LDS bounce) — proven r4 =================
__global__ __launch_bounds__(512, 4)
void k1_enc(const float* __restrict__ cur_x, const float* __restrict__ nb_x,
            const unsigned short* __restrict__ wsb, const float* __restrict__ wsp,
            unsigned short* __restrict__ wse) {
  __shared__ __align__(16) unsigned short s_w1[4096];
  __shared__ __align__(16) unsigned short s_w2[16384];
  __shared__ __align__(16) unsigned short s_h1[8][16 * 136];
  __shared__ float s_prm[6 * 128];

  const int tid = threadIdx.x;
  const int wv = tid >> 6, l = tid & 63, l15 = l & 15, lg = l >> 4;

  ((uint4*)s_w1)[tid] = ((const uint4*)(wsb + W1P))[tid];
#pragma unroll
  for (int i = 0; i < 4; ++i)
    ((uint4*)s_w2)[tid + i * 512] = ((const uint4*)(wsb + W2))[tid + i * 512];
  for (int i = tid; i < 768; i += 512) s_prm[i] = wsp[i];
  __syncthreads();

  unsigned short* h1 = &s_h1[wv][0];

  auto ln_t = [&](float (&acc)[8][4], int bs, int gs, int es, bool relu) {
#pragma unroll
    for (int ct = 0; ct < 8; ++ct) {
      float4 bb = *(const float4*)&s_prm[bs * 128 + ct * 16 + lg * 4];
      acc[ct][0] += bb.x; acc[ct][1] += bb.y; acc[ct][2] += bb.z; acc[ct][3] += bb.w;
    }
    float sm = 0.f, sq = 0.f;
#pragma unroll
    for (int ct = 0; ct < 8; ++ct)
#pragma unroll
      for (int r = 0; r < 4; ++r) { sm += acc[ct][r]; sq = fmaf(acc[ct][r], acc[ct][r], sq); }
    sm += __shfl_xor(sm, 16); sq += __shfl_xor(sq, 16);
    sm += __shfl_xor(sm, 32); sq += __shfl_xor(sq, 32);
    float mean = sm * 0.0078125f;
    float var = fmaf(sq, 0.0078125f, -mean * mean);
    float inv = rsqrtf(var + 1e-5f);
#pragma unroll
    for (int ct = 0; ct < 8; ++ct) {
      float4 gg = *(const float4*)&s_prm[gs * 128 + ct * 16 + lg * 4];
      float4 ee = *(const float4*)&s_prm[es * 128 + ct * 16 + lg * 4];
      float ga[4] = {gg.x, gg.y, gg.z, gg.w}, ea[4] = {ee.x, ee.y, ee.z, ee.w};
#pragma unroll
      for (int r = 0; r < 4; ++r) {
        float v = (acc[ct][r] - mean) * inv * ga[r] + ea[r];
        acc[ct][r] = relu ? fmaxf(v, 0.f) : v;
      }
    }
  };

#pragma unroll 1
  for (int t = blockIdx.x * 8 + wv; t < 18432; t += 9216) {
    asm volatile("s_waitcnt lgkmcnt(0)" ::: "memory");
    const bool isnb = t < 16384;
    const float* src = isnb ? nb_x + (size_t)t * 256
                            : cur_x + ((size_t)t - 16384) * 256;
    unsigned short* dst = wse + (isnb ? (size_t)NBE + (size_t)t * 2048
                                      : (size_t)CURE + ((size_t)t - 16384) * 2048);

    float4 fin = ((const float4*)src)[l];
    {
      uint2 u;
      u.x = (unsigned)f2bf(fin.x) | ((unsigned)f2bf(fin.y) << 16);
      u.y = (unsigned)f2bf(fin.z) | ((unsigned)f2bf(fin.w) << 16);
      *(uint2*)(h1 + (l >> 2) * 16 + (l & 3) * 4) = u;
    }
    bf16x8 bx = (bf16x8){0, 0, 0, 0, 0, 0, 0, 0};
    if (lg < 2) bx = *(const bf16x8*)(h1 + l15 * 16 + lg * 8);

    float acc[8][4];
#pragma unroll
    for (int ct = 0; ct < 8; ++ct) {
      f32x4 a = {0.f, 0.f, 0.f, 0.f};
      a = mfma16(frag32(s_w1, ct * 16 + l15, lg), bx, a);
      acc[ct][0] = a[0]; acc[ct][1] = a[1]; acc[ct][2] = a[2]; acc[ct][3] = a[3];
    }
    ln_t(acc, 0, 1, 2, true);
#pragma unroll
    for (int ct = 0; ct < 8; ++ct) {
      uint2 u;
      u.x = (unsigned)f2bf(acc[ct][0]) | ((unsigned)f2bf(acc[ct][1]) << 16);
      u.y = (unsigned)f2bf(acc[ct][2]) | ((unsigned)f2bf(acc[ct][3]) << 16);
      *(uint2*)(h1 + l15 * 136 + ct * 16 + lg * 4) = u;
    }

    bf16x8 bh[4];
#pragma unroll
    for (int kk = 0; kk < 4; ++kk)
      bh[kk] = *(const bf16x8*)(h1 + l15 * 136 + kk * 32 + lg * 8);
#pragma unroll
    for (int ct = 0; ct < 8; ++ct) {
      f32x4 a = {0.f, 0.f, 0.f, 0.f};
#pragma unroll
      for (int kk = 0; kk < 4; ++kk)
        a = mfma16(frag128(s_w2, ct * 16 + l15, kk, lg), bh[kk], a);
      acc[ct][0] = a[0]; acc[ct][1] = a[1]; acc[ct][2] = a[2]; acc[ct][3] = a[3];
    }
    ln_t(acc, 3, 4, 5, false);

#pragma unroll
    for (int ct = 0; ct < 8; ++ct) {
      uint2 u;
      u.x = (unsigned)f2bf(acc[ct][0]) | ((unsigned)f2bf(acc[ct][1]) << 16);
      u.y = (unsigned)f2bf(acc[ct][2]) | ((unsigned)f2bf(acc[ct][3]) << 16);
      int c = ct * 2 + (lg >> 1);
      *(uint2*)(h1 + l15 * 128 + ((c ^ l15) << 3) + (lg & 1) * 4) = u;
    }
#pragma unroll
    for (int i = 0; i < 4; ++i) {
      int R = i * 4 + lg;
      int j = l15;
      uint4 u = *(const uint4*)(h1 + R * 128 + ((j ^ R) << 3));
      ((uint4*)dst)[i * 64 + l] = u;
    }
  }
}

// ===== K2 v3: wave-private, zero-barrier, PER-HEAD reassociated attention =====
// Fix vs r5: attention is 4-head. qk_h = Wk_h^T q_h (one K=32 MFMA per 16-chan tile,
// bounced via bufC into qf regs); scores all heads in ONE nb pass; per-head in-lane
// softmax; per head: pnb_h = sum_n p[h][n]*nb_n -> bufC -> ctx chans 32h..32h+31.
__global__ __launch_bounds__(256, 2)
void k2_head(const int* __restrict__ nb_mask,
             const unsigned short* __restrict__ wsb, const float* __restrict__ wsp,
             float* __restrict__ out) {
  __shared__ __align__(16) unsigned short s_buf[4][3][16 * 136];  // per-wave cur/work/scratch
  __shared__ float s_prm[NPRM];
  __shared__ int s_mask[64];

  const int tid = threadIdx.x;
  const int wv = tid >> 6, l = tid & 63, l15 = l & 15, lg = l >> 4;
  const int ew = (blockIdx.x * 4 + wv) * 16;     // this wave's first element
  unsigned short* bufA = &s_buf[wv][0][0];
  unsigned short* bufB = &s_buf[wv][1][0];
  unsigned short* bufC = &s_buf[wv][2][0];

  for (int i = tid; i < NPRM; i += 256) s_prm[i] = wsp[i];
  {
    const uint4* src = (const uint4*)(wsb + CURE + (size_t)ew * 128);
#pragma unroll
    for (int i = 0; i < 4; ++i) {
      int idx = i * 64 + l, row = idx >> 4, ch = idx & 15;
      *(uint4*)(bufA + row * 136 + ch * 8) = src[idx];
    }
  }
  if (l < 16) {
    int m = 0; const int* mp = nb_mask + (size_t)(ew + l) * 8;
#pragma unroll
    for (int n = 0; n < 8; ++n) m |= (mp[n] > 0) << n;
    s_mask[wv * 16 + l] = m;
  }
  __syncthreads();   // ONLY barrier (covers s_prm; bufA/mask are wave-private)

  float acc[8][4];

  auto ln_t = [&](int bs, int gs, int es, bool relu) {
#pragma unroll
    for (int ct = 0; ct < 8; ++ct) {
      float4 bb = *(const float4*)&s_prm[bs * 128 + ct * 16 + lg * 4];
      acc[ct][0] += bb.x; acc[ct][1] += bb.y; acc[ct][2] += bb.z; acc[ct][3] += bb.w;
    }
    float sm = 0.f, sq = 0.f;
#pragma unroll
    for (int ct = 0; ct < 8; ++ct)
#pragma unroll
      for (int r = 0; r < 4; ++r) { sm += acc[ct][r]; sq = fmaf(acc[ct][r], acc[ct][r], sq); }
    sm += __shfl_xor(sm, 16); sq += __shfl_xor(sq, 16);
    sm += __shfl_xor(sm, 32); sq += __shfl_xor(sq, 32);
    float mean = sm * 0.0078125f;
    float var = fmaf(sq, 0.0078125f, -mean * mean);
    float inv = rsqrtf(var + 1e-5f);
#pragma unroll
    for (int ct = 0; ct < 8; ++ct) {
      float4 gg = *(const float4*)&s_prm[gs * 128 + ct * 16 + lg * 4];
      float4 ee = *(const float4*)&s_prm[es * 128 + ct * 16 + lg * 4];
      float ga[4] = {gg.x, gg.y, gg.z, gg.w}, ea[4] = {ee.x, ee.y, ee.z, ee.w};
#pragma unroll
      for (int r = 0; r < 4; ++r) {
        float v = (acc[ct][r] - mean) * inv * ga[r] + ea[r];
        acc[ct][r] = relu ? fmaxf(v, 0.f) : v;
      }
    }
  };

  // ---- Q = cur @ Wq^T (+bq, *1/sqrt(32)) -> bufB [elem][chan] bf16 ----
  {
    bf16x8 b[4];
#pragma unroll
    for (int kk = 0; kk < 4; ++kk) b[kk] = *(const bf16x8*)(bufA + l15 * 136 + kk * 32 + lg * 8);
#pragma unroll
    for (int ct = 0; ct < 8; ++ct) {
      f32x4 a4 = {0.f, 0.f, 0.f, 0.f};
#pragma unroll
      for (int kk = 0; kk < 4; ++kk) {
        bf16x8 w = *(const bf16x8*)(wsb + WQr + (ct * 16 + l15) * 128 + kk * 32 + lg * 8);
        a4 = mfma16(w, b[kk], a4);
      }
      float4 bb = *(const float4*)&s_prm[6 * 128 + ct * 16 + lg * 4];
      uint2 u;
      u.x = (unsigned)f2bf((a4[0] + bb.x) * 0.17677669529663687f)
          | ((unsigned)f2bf((a4[1] + bb.y) * 0.17677669529663687f) << 16);
      u.y = (unsigned)f2bf((a4[2] + bb.z) * 0.17677669529663687f)
          | ((unsigned)f2bf((a4[3] + bb.w) * 0.17677669529663687f) << 16);
      *(uint2*)(bufB + l15 * 136 + ct * 16 + lg * 4) = u;
    }
  }
  __builtin_amdgcn_sched_barrier(0);

  // ---- qk_h = Wk_h^T q_h per head -> qf regs (via bufC bounce) ----
  bf16x8 qf[4][4];
#pragma unroll
  for (int h = 0; h < 4; ++h) {
    bf16x8 qb = *(const bf16x8*)(bufB + l15 * 136 + h * 32 + lg * 8);
    __builtin_amdgcn_sched_barrier(0);
#pragma unroll
    for (int ct = 0; ct < 8; ++ct) {
      bf16x8 w = *(const bf16x8*)(wsb + WKt + (ct * 16 + l15) * 128 + h * 32 + lg * 8);
      f32x4 a4 = {0.f, 0.f, 0.f, 0.f};
      a4 = mfma16(w, qb, a4);
      uint2 u;
      u.x = (unsigned)f2bf(a4[0]) | ((unsigned)f2bf(a4[1]) << 16);
      u.y = (unsigned)f2bf(a4[2]) | ((unsigned)f2bf(a4[3]) << 16);
      *(uint2*)(bufC + l15 * 136 + ct * 16 + lg * 4) = u;
    }
    __builtin_amdgcn_sched_barrier(0);
#pragma unroll
    for (int kk = 0; kk < 4; ++kk)
      qf[h][kk] = *(const bf16x8*)(bufC + l15 * 136 + kk * 32 + lg * 8);
    __builtin_amdgcn_sched_barrier(0);
  }

  // ---- scores: ONE pass over nb, all 4 heads; per-head in-lane masked softmax ----
  float pe[4][8];
  {
    const unsigned short* nbp = wsb + NBE + (size_t)(ew + l15) * 1024;
    float ps[4][8];
#pragma unroll
    for (int h = 0; h < 4; ++h)
#pragma unroll
      for (int n = 0; n < 8; ++n) ps[h][n] = 0.f;
#pragma unroll
    for (int n = 0; n < 8; ++n) {
#pragma unroll
      for (int kk = 0; kk < 4; ++kk) {
        bf16x8 nf = *(const bf16x8*)(nbp + n * 128 + kk * 32 + lg * 8);
#pragma unroll
        for (int i = 0; i < 8; ++i) {
          float nv = bf2f((unsigned short)nf[i]);
          ps[0][n] = fmaf(nv, bf2f((unsigned short)qf[0][kk][i]), ps[0][n]);
          ps[1][n] = fmaf(nv, bf2f((unsigned short)qf[1][kk][i]), ps[1][n]);
          ps[2][n] = fmaf(nv, bf2f((unsigned short)qf[2][kk][i]), ps[2][n]);
          ps[3][n] = fmaf(nv, bf2f((unsigned short)qf[3][kk][i]), ps[3][n]);
        }
      }
    }
#pragma unroll
    for (int h = 0; h < 4; ++h)
#pragma unroll
      for (int n = 0; n < 8; ++n) {
        ps[h][n] += __shfl_xor(ps[h][n], 16);
        ps[h][n] += __shfl_xor(ps[h][n], 32);
      }
    int m = s_mask[wv * 16 + l15];
    bool all = (m == 0);
#pragma unroll
    for (int h = 0; h < 4; ++h) {
      float mx = -1e30f;
#pragma unroll
      for (int n = 0; n < 8; ++n) {
        bool u = all || ((m >> n) & 1);
        mx = fmaxf(mx, u ? ps[h][n] : -1e30f);
      }
      float su = 0.f;
#pragma unroll
      for (int n = 0; n < 8; ++n) {
        bool u = all || ((m >> n) & 1);
        pe[h][n] = u ? __expf(ps[h][n] - mx) : 0.f;
        su += pe[h][n];
      }
      float inv = 1.f / su;
#pragma unroll
      for (int n = 0; n < 8; ++n) pe[h][n] *= inv;
    }
  }
  __builtin_amdgcn_sched_barrier(0);

  // ---- per head: pnb_h -> bufC; ctx chans 32h..32h+31 = pnb_h @ Wv^T (+bv) -> bufB ----
  {
    const unsigned short* nbp = wsb + NBE + (size_t)(ew + l15) * 1024;
#pragma unroll
    for (int h = 0; h < 4; ++h) {
      float pn[4][8];
#pragma unroll
      for (int kk = 0; kk < 4; ++kk)
#pragma unroll
        for (int i = 0; i < 8; ++i) pn[kk][i] = 0.f;
#pragma unroll
      for (int n = 0; n < 8; ++n) {
        float pv = pe[h][n];
#pragma unroll
        for (int kk = 0; kk < 4; ++kk) {
          bf16x8 nf = *(const bf16x8*)(nbp + n * 128 + kk * 32 + lg * 8);
#pragma unroll
          for (int i = 0; i < 8; ++i)
            pn[kk][i] = fmaf(bf2f((unsigned short)nf[i]), pv, pn[kk][i]);
        }
      }
#pragma unroll
      for (int kk = 0; kk < 4; ++kk) {
        uint4 u;
        u.x = (unsigned)f2bf(pn[kk][0]) | ((unsigned)f2bf(pn[kk][1]) << 16);
        u.y = (unsigned)f2bf(pn[kk][2]) | ((unsigned)f2bf(pn[kk][3]) << 16);
        u.z = (unsigned)f2bf(pn[kk][4]) | ((unsigned)f2bf(pn[kk][5]) << 16);
        u.w = (unsigned)f2bf(pn[kk][6]) | ((unsigned)f2bf(pn[kk][7]) << 16);
        *(uint4*)(bufC + l15 * 136 + kk * 32 + lg * 8) = u;
      }
      __builtin_amdgcn_sched_barrier(0);
#pragma unroll
      for (int cc = 0; cc < 2; ++cc) {
        int ct = h * 2 + cc;
        f32x4 a4 = {0.f, 0.f, 0.f, 0.f};
#pragma unroll
        for (int kk = 0; kk < 4; ++kk) {
          bf16x8 b = *(const bf16x8*)(bufC + l15 * 136 + kk * 32 + lg * 8);
          a4 = mfma16(frag128(wsb + WVW, ct * 16 + l15, kk, lg), b, a4);
        }
        float4 bb = *(const float4*)&s_prm[8 * 128 + ct * 16 + lg * 4];
        uint2 u;
        u.x = (unsigned)f2bf(a4[0] + bb.x) | ((unsigned)f2bf(a4[1] + bb.y) << 16);
        u.y = (unsigned)f2bf(a4[2] + bb.z) | ((unsigned)f2bf(a4[3] + bb.w) << 16);
        *(uint2*)(bufB + l15 * 136 + ct * 16 + lg * 4) = u;
      }
      __builtin_amdgcn_sched_barrier(0);
    }
  }

  // ---- OUT = ctx @ out_w^T (+out_b), LN(an), agg select -> bufB ----
  {
    bf16x8 b[4];
#pragma unroll
    for (int kk = 0; kk < 4; ++kk) b[kk] = *(const bf16x8*)(bufB + l15 * 136 + kk * 32 + lg * 8);
    __builtin_amdgcn_sched_barrier(0);
#pragma unroll
    for (int ct = 0; ct < 8; ++ct) {
      f32x4 a4 = {0.f, 0.f, 0.f, 0.f};
#pragma unroll
      for (int kk = 0; kk < 4; ++kk) {
        bf16x8 w = *(const bf16x8*)(wsb + OWr + (ct * 16 + l15) * 128 + kk * 32 + lg * 8);
        a4 = mfma16(w, b[kk], a4);
      }
      acc[ct][0] = a4[0]; acc[ct][1] = a4[1]; acc[ct][2] = a4[2]; acc[ct][3] = a4[3];
    }
    ln_t(9, 10, 11, false);
    int m = s_mask[wv * 16 + l15];
#pragma unroll
    for (int ct = 0; ct < 8; ++ct) {
      uint2 cu = *(const uint2*)(bufA + l15 * 136 + ct * 16 + lg * 4);
      unsigned short a0 = m ? f2bf(acc[ct][0]) : (unsigned short)(cu.x & 0xffff);
      unsigned short a1 = m ? f2bf(acc[ct][1]) : (unsigned short)(cu.x >> 16);
      unsigned short a2 = m ? f2bf(acc[ct][2]) : (unsigned short)(cu.y & 0xffff);
      unsigned short a3 = m ? f2bf(acc[ct][3]) : (unsigned short)(cu.y >> 16);
      uint2 u;
      u.x = (unsigned)a0 | ((unsigned)a1 << 16);
      u.y = (unsigned)a2 | ((unsigned)a3 << 16);
      *(uint2*)(bufB + l15 * 136 + ct * 16 + lg * 4) = u;
    }
  }
  __builtin_amdgcn_sched_barrier(0);

  // ---- P1 = cur@P1A^T + agg@P1B^T (+b), LN, ReLU -> bufB (hh) ----
  {
    bf16x8 bc[4], bg[4];
#pragma unroll
    for (int kk = 0; kk < 4; ++kk) {
      bc[kk] = *(const bf16x8*)(bufA + l15 * 136 + kk * 32 + lg * 8);
      bg[kk] = *(const bf16x8*)(bufB + l15 * 136 + kk * 32 + lg * 8);
    }
    __builtin_amdgcn_sched_barrier(0);
#pragma unroll
    for (int ct = 0; ct < 8; ++ct) {
      f32x4 a4 = {0.f, 0.f, 0.f, 0.f};
#pragma unroll
      for (int kk = 0; kk < 4; ++kk) {
        bf16x8 w = *(const bf16x8*)(wsb + P1Ar + (ct * 16 + l15) * 128 + kk * 32 + lg * 8);
        a4 = mfma16(w, bc[kk], a4);
      }
#pragma unroll
      for (int kk = 0; kk < 4; ++kk) {
        bf16x8 w = *(const bf16x8*)(wsb + P1Br + (ct * 16 + l15) * 128 + kk * 32 + lg * 8);
        a4 = mfma16(w, bg[kk], a4);
      }
      acc[ct][0] = a4[0]; acc[ct][1] = a4[1]; acc[ct][2] = a4[2]; acc[ct][3] = a4[3];
    }
    ln_t(12, 13, 14, true);
#pragma unroll
    for (int ct = 0; ct < 8; ++ct) {
      uint2 u;
      u.x = (unsigned)f2bf(acc[ct][0]) | ((unsigned)f2bf(acc[ct][1]) << 16);
      u.y = (unsigned)f2bf(acc[ct][2]) | ((unsigned)f2bf(acc[ct][3]) << 16);
      *(uint2*)(bufB + l15 * 136 + ct * 16 + lg * 4) = u;
    }
  }
  __builtin_amdgcn_sched_barrier(0);

  // ---- P2 (+b), LN(p2) -> global out ----
  {
    bf16x8 b[4];
#pragma unroll
    for (int kk = 0; kk < 4; ++kk) b[kk] = *(const bf16x8*)(bufB + l15 * 136 + kk * 32 + lg * 8);
    __builtin_amdgcn_sched_barrier(0);
#pragma unroll
    for (int ct = 0; ct < 8; ++ct) {
      f32x4 a4 = {0.f, 0.f, 0.f, 0.f};
#pragma unroll
      for (int kk = 0; kk < 4; ++kk) {
        bf16x8 w = *(const bf16x8*)(wsb + P2r + (ct * 16 + l15) * 128 + kk * 32 + lg * 8);
        a4 = mfma16(w, b[kk], a4);
      }
      acc[ct][0] = a4[0]; acc[ct][1] = a4[1]; acc[ct][2] = a4[2]; acc[ct][3] = a4[3];
    }
    ln_t(15, 16, 17, false);
    float* op = out + (size_t)(ew + l15) * 128;
#pragma unroll
    for (int ct = 0; ct < 8; ++ct)
      *(float4*)(op + ct * 16 + lg * 4) =
          make_float4(acc[ct][0], acc[ct][1], acc[ct][2], acc[ct][3]);
  }
}

// ================= fallback monolith (round-2, proven) =================
__global__ __launch_bounds__(NTH, 1)
void gcn_mfma(const float* __restrict__ cur_x, const float* __restrict__ nb_x,
              const int* __restrict__ nb_mask,
              const unsigned short* __restrict__ wsb, const float* __restrict__ wsp,
              float* __restrict__ out) {
  __shared__ __align__(16) unsigned short s_stage[20480];
  __shared__ __align__(16) unsigned short s_X[144 * 32];
  __shared__ __align__(16) unsigned short s_H[144 * 128];
  __shared__ __align__(16) unsigned short s_Enb[128 * 128];
  __shared__ __align__(16) unsigned short s_Ecur[16 * 128];
  __shared__ __align__(16) float s_q[16 * 132];
  __shared__ __align__(16) float s_p[16 * 32];
  __shared__ __align__(16) unsigned short s_ctx[16 * 128];
  __shared__ __align__(16) unsigned short s_agg[16 * 128];
  __shared__ __align__(16) unsigned short s_hh[16 * 128];
  __shared__ float s_prm[NPRM];
  __shared__ int s_mask[16];

  const int tid = threadIdx.x;
  const int wv = tid >> 6, l = tid & 63, l15 = l & 15, lg = l >> 4;
  const int sub = l >> 5, l32 = l & 31;
  const int ebase = blockIdx.x * TBE;
  const int eo = wv * 2 + sub;

  auto stage = [&](int srcOff) {
    const uint4* s = (const uint4*)(wsb + srcOff);
    uint4* d = (uint4*)s_stage;
#pragma unroll
    for (int i = 0; i < 4; ++i) d[tid + i * NTH] = s[tid + i * NTH];
  };
  auto ln_epi = [&](float (&vals)[8][4], int bslot, int gslot, int beslot, bool relu) {
    float sm[4] = {0, 0, 0, 0}, sq[4] = {0, 0, 0, 0};
#pragma unroll
    for (int nt = 0; nt < 8; ++nt) {
      float b = s_prm[bslot * 128 + nt * 16 + l15];
#pragma unroll
      for (int r = 0; r < 4; ++r) {
        float v = vals[nt][r] + b; vals[nt][r] = v;
        sm[r] += v; sq[r] = fmaf(v, v, sq[r]);
      }
    }
#pragma unroll
    for (int off = 8; off >= 1; off >>= 1)
#pragma unroll
      for (int r = 0; r < 4; ++r) {
        sm[r] += __shfl_xor(sm[r], off);
        sq[r] += __shfl_xor(sq[r], off);
      }
    float mean[4], inv[4];
#pragma unroll
    for (int r = 0; r < 4; ++r) {
      mean[r] = sm[r] * 0.0078125f;
      float var = fmaf(sq[r], 0.0078125f, -mean[r] * mean[r]);
      inv[r] = rsqrtf(var + 1e-5f);
    }
#pragma unroll
    for (int nt = 0; nt < 8; ++nt) {
      int col = nt * 16 + l15;
      float g = s_prm[gslot * 128 + col], be = s_prm[beslot * 128 + col];
#pragma unroll
      for (int r = 0; r < 4; ++r) {
        float v = (vals[nt][r] - mean[r]) * inv[r] * g + be;
        vals[nt][r] = relu ? fmaxf(v, 0.f) : v;
      }
    }
  };

  {
    const uint4* s = (const uint4*)(wsb + W1P);
    ((uint4*)(s_stage + 16384))[tid] = s[tid];
  }
  for (int i = tid; i < NPRM; i += NTH) s_prm[i] = wsp[i];
  for (int i = tid; i < 4608; i += NTH) {
    int row = i >> 5, col = i & 31;
    int e = (row * 57) >> 9, kind = row - e * 9;
    float v = 0.f;
    if (col < 16) {
      int ge = ebase + e;
      v = (kind == 0) ? cur_x[(size_t)ge * 16 + col]
                      : nb_x[((size_t)ge * 8 + (kind - 1)) * 16 + col];
    }
    s_X[row * 32 + ((((col >> 3) ^ (row & 3)) << 3) | (col & 7))] = f2bf(v);
  }
  if (tid < 16) {
    int m = 0; const int* mp = nb_mask + (size_t)(ebase + tid) * 8;
#pragma unroll
    for (int n = 0; n < 8; ++n) m |= (mp[n] > 0) << n;
    s_mask[tid] = m;
  }
  __syncthreads();

  stage(W2);
  for (int mt = wv; mt < 9; mt += 8) {
    bf16x8 a = frag32(s_X, mt * 16 + l15, lg);
    float vals[8][4];
#pragma unroll
    for (int nt = 0; nt < 8; ++nt) {
      f32x4 acc = {0.f, 0.f, 0.f, 0.f};
      acc = mfma16(a, frag32(s_stage + 16384, nt * 16 + l15, lg), acc);
#pragma unroll
      for (int r = 0; r < 4; ++r) vals[nt][r] = acc[r];
    }
    ln_epi(vals, 0, 1, 2, true);
#pragma unroll
    for (int nt = 0; nt < 8; ++nt)
#pragma unroll
      for (int r = 0; r < 4; ++r)
        st_bf16(s_H, mt * 16 + lg * 4 + r, nt * 16 + l15, vals[nt][r]);
  }
  __syncthreads();

  for (int mt = wv; mt < 9; mt += 8) {
    bf16x8 a[4];
#pragma unroll
    for (int kk = 0; kk < 4; ++kk) a[kk] = frag128(s_H, mt * 16 + l15, kk, lg);
    float vals[8][4];
#pragma unroll
    for (int nt = 0; nt < 8; ++nt) {
      f32x4 acc = {0.f, 0.f, 0.f, 0.f};
#pragma unroll
      for (int kk = 0; kk < 4; ++kk)
        acc = mfma16(a[kk], frag128(s_stage, nt * 16 + l15, kk, lg), acc);
#pragma unroll
      for (int r = 0; r < 4; ++r) vals[nt][r] = acc[r];
    }
    ln_epi(vals, 3, 4, 5, false);
#pragma unroll
    for (int nt = 0; nt < 8; ++nt) {
      int col = nt * 16 + l15;
#pragma unroll
      for (int r = 0; r < 4; ++r) {
        int R = mt * 16 + lg * 4 + r;
        int e = (R * 57) >> 9, kind = R - e * 9;
        if (kind == 0) st_bf16(s_Ecur, e, col, vals[nt][r]);
        else           st_bf16(s_Enb, e * 8 + kind - 1, col, vals[nt][r]);
      }
    }
  }
  __syncthreads();
  stage(WQ);
  __syncthreads();

  {
    f32x4 acc = {0.f, 0.f, 0.f, 0.f};
#pragma unroll
    for (int kk = 0; kk < 4; ++kk)
      acc = mfma16(frag128(s_Ecur, l15, kk, lg), frag128(s_stage, wv * 16 + l15, kk, lg), acc);
    int col = wv * 16 + l15; float bq = s_prm[6 * 128 + col];
#pragma unroll
    for (int r = 0; r < 4; ++r) s_q[(lg * 4 + r) * 132 + col] = acc[r] + bq;
  }
  __syncthreads();
  stage(WK);
  __syncthreads();

  {
    bf16x8 b[4];
#pragma unroll
    for (int kk = 0; kk < 4; ++kk) b[kk] = frag128(s_stage, wv * 16 + l15, kk, lg);
    int col = wv * 16 + l15; float bk = s_prm[7 * 128 + col];
#pragma unroll
    for (int mt = 0; mt < 8; ++mt) {
      f32x4 acc = {0.f, 0.f, 0.f, 0.f};
#pragma unroll
      for (int kk = 0; kk < 4; ++kk)
        acc = mfma16(frag128(s_Enb, mt * 16 + l15, kk, lg), b[kk], acc);
#pragma unroll
      for (int r = 0; r < 4; ++r)
        st_bf16(s_H, mt * 16 + lg * 4 + r, col, acc[r] + bk);
    }
  }
  __syncthreads();

  stage(WVW);
  {
    int h = l32 >> 3, n = l32 & 7;
    int krow = eo * 8 + n;
    float dot = 0.f;
#pragma unroll
    for (int j = 0; j < 4; ++j) {
      bf16x8 kf = *(const bf16x8*)(s_H + krow * 128 + (((h * 4 + j) ^ (krow & 7)) << 3));
      const float* qp = s_q + eo * 132 + h * 32 + j * 8;
      float4 q0 = *(const float4*)qp, q1 = *(const float4*)(qp + 4);
      dot = fmaf(__uint_as_float(((unsigned)(unsigned short)kf[0]) << 16), q0.x, dot);
      dot = fmaf(__uint_as_float(((unsigned)(unsigned short)kf[1]) << 16), q0.y, dot);
      dot = fmaf(__uint_as_float(((unsigned)(unsigned short)kf[2]) << 16), q0.z, dot);
      dot = fmaf(__uint_as_float(((unsigned)(unsigned short)kf[3]) << 16), q0.w, dot);
      dot = fmaf(__uint_as_float(((unsigned)(unsigned short)kf[4]) << 16), q1.x, dot);
      dot = fmaf(__uint_as_float(((unsigned)(unsigned short)kf[5]) << 16), q1.y, dot);
      dot = fmaf(__uint_as_float(((unsigned)(unsigned short)kf[6]) << 16), q1.z, dot);
      dot = fmaf(__uint_as_float(((unsigned)(unsigned short)kf[7]) << 16), q1.w, dot);
    }
    float sc = dot * 0.17677669529663687f;
    int m = s_mask[eo];
    bool use = (m == 0) || ((m >> n) & 1);
    float scm = use ? sc : -1e30f;
    float mx = scm;
#pragma unroll
    for (int off = 4; off >= 1; off >>= 1) mx = fmaxf(mx, __shfl_xor(mx, off));
    float p = use ? __expf(sc - mx) : 0.f;
    float sum = p;
#pragma unroll
    for (int off = 4; off >= 1; off >>= 1) sum += __shfl_xor(sum, off);
    s_p[eo * 32 + h * 8 + n] = p / sum;
  }
  __syncthreads();

  {
    bf16x8 b[4];
#pragma unroll
    for (int kk = 0; kk < 4; ++kk) b[kk] = frag128(s_stage, wv * 16 + l15, kk, lg);
    int col = wv * 16 + l15; float bv = s_prm[8 * 128 + col];
#pragma unroll
    for (int mt = 0; mt < 8; ++mt) {
      f32x4 acc = {0.f, 0.f, 0.f, 0.f};
#pragma unroll
      for (int kk = 0; kk < 4; ++kk)
        acc = mfma16(frag128(s_Enb, mt * 16 + l15, kk, lg), b[kk], acc);
#pragma unroll
      for (int r = 0; r < 4; ++r)
        st_bf16(s_H, mt * 16 + lg * 4 + r, col, acc[r] + bv);
    }
  }
  __syncthreads();

  stage(OW);
  {
#pragma unroll
    for (int cc = 0; cc < 4; ++cc) {
      int col = l32 + 32 * cc;
      float c = 0.f;
#pragma unroll
      for (int n = 0; n < 8; ++n)
        c = fmaf(s_p[eo * 32 + cc * 8 + n], ld_bf16(s_H, eo * 8 + n, col), c);
      st_bf16(s_ctx, eo, col, c);
    }
  }
  __syncthreads();

  {
    f32x4 acc = {0.f, 0.f, 0.f, 0.f};
#pragma unroll
    for (int kk = 0; kk < 4; ++kk)
      acc = mfma16(frag128(s_ctx, l15, kk, lg), frag128(s_stage, wv * 16 + l15, kk, lg), acc);
    int col = wv * 16 + l15; float bo = s_prm[9 * 128 + col];
#pragma unroll
    for (int r = 0; r < 4; ++r) s_q[(lg * 4 + r) * 132 + col] = acc[r] + bo;
  }
  __syncthreads();

  stage(P1A);
  {
    float4 x = *(const float4*)&s_q[eo * 132 + l32 * 4];
    float s = x.x + x.y + x.z + x.w;
    float qq = fmaf(x.x, x.x, fmaf(x.y, x.y, fmaf(x.z, x.z, x.w * x.w)));
#pragma unroll
    for (int off = 16; off >= 1; off >>= 1) { s += __shfl_xor(s, off); qq += __shfl_xor(qq, off); }
    float mean = s * 0.0078125f;
    float var = fmaf(qq, 0.0078125f, -mean * mean);
    float inv = rsqrtf(var + 1e-5f);
    int m = s_mask[eo];
    float xa[4] = {x.x, x.y, x.z, x.w}, r4[4];
#pragma unroll
    for (int c = 0; c < 4; ++c) {
      int col = l32 * 4 + c;
      float v = (xa[c] - mean) * inv * s_prm[10 * 128 + col] + s_prm[11 * 128 + col];
      r4[c] = m ? v : ld_bf16(s_Ecur, eo, col);
    }
    uint2 uu;
    uu.x = (unsigned)f2bf(r4[0]) | ((unsigned)f2bf(r4[1]) << 16);
    uu.y = (unsigned)f2bf(r4[2]) | ((unsigned)f2bf(r4[3]) << 16);
    *(uint2*)(s_agg + eo * 128 + (((l32 >> 1) ^ (eo & 7)) << 3) + (l32 & 1) * 4) = uu;
  }
  __syncthreads();

  f32x4 accP = {0.f, 0.f, 0.f, 0.f};
#pragma unroll
  for (int kk = 0; kk < 4; ++kk)
    accP = mfma16(frag128(s_Ecur, l15, kk, lg), frag128(s_stage, wv * 16 + l15, kk, lg), accP);
  __syncthreads();
  stage(P1B);
  __syncthreads();
  {
#pragma unroll
    for (int kk = 0; kk < 4; ++kk)
      accP = mfma16(frag128(s_agg, l15, kk, lg), frag128(s_stage, wv * 16 + l15, kk, lg), accP);
    int col = wv * 16 + l15; float b = s_prm[12 * 128 + col];
#pragma unroll
    for (int r = 0; r < 4; ++r) s_q[(lg * 4 + r) * 132 + col] = accP[r] + b;
  }
  __syncthreads();

  stage(P2W);
  {
    float4 x = *(const float4*)&s_q[eo * 132 + l32 * 4];
    float s = x.x + x.y + x.z + x.w;
    float qq = fmaf(x.x, x.x, fmaf(x.y, x.y, fmaf(x.z, x.z, x.w * x.w)));
#pragma unroll
    for (int off = 16; off >= 1; off >>= 1) { s += __shfl_xor(s, off); qq += __shfl_xor(qq, off); }
    float mean = s * 0.0078125f;
    float var = fmaf(qq, 0.0078125f, -mean * mean);
    float inv = rsqrtf(var + 1e-5f);
    float xa[4] = {x.x, x.y, x.z, x.w}, r4[4];
#pragma unroll
    for (int c = 0; c < 4; ++c) {
      int col = l32 * 4 + c;
      r4[c] = fmaxf((xa[c] - mean) * inv * s_prm[13 * 128 + col] + s_prm[14 * 128 + col], 0.f);
    }
    uint2 uu;
    uu.x = (unsigned)f2bf(r4[0]) | ((unsigned)f2bf(r4[1]) << 16);
    uu.y = (unsigned)f2bf(r4[2]) | ((unsigned)f2bf(r4[3]) << 16);
    *(uint2*)(s_hh + eo * 128 + (((l32 >> 1) ^ (eo & 7)) << 3) + (l32 & 1) * 4) = uu;
  }
  __syncthreads();

  {
    f32x4 acc = {0.f, 0.f, 0.f, 0.f};
#pragma unroll
    for (int kk = 0; kk < 4; ++kk)
      acc = mfma16(frag128(s_hh, l15, kk, lg), frag128(s_stage, wv * 16 + l15, kk, lg), acc);
    int col = wv * 16 + l15; float b = s_prm[15 * 128 + col];
#pragma unroll
    for (int r = 0; r < 4; ++r) s_q[(lg * 4 + r) * 132 + col] = acc[r] + b;
  }
  __syncthreads();

  {
    float4 x = *(const float4*)&s_q[eo * 132 + l32 * 4];
    float s = x.x + x.y + x.z + x.w;
    float qq = fmaf(x.x, x.x, fmaf(x.y, x.y, fmaf(x.z, x.z, x.w * x.w)));
#pragma unroll
    for (int off = 16; off >= 1; off >>= 1) { s += __shfl_xor(s, off); qq += __shfl_xor(qq, off); }
    float mean = s * 0.0078125f;
    float var = fmaf(qq, 0.0078125f, -mean * mean);
    float inv = rsqrtf(var + 1e-5f);
    float xa[4] = {x.x, x.y, x.z, x.w};
    float4 o;
    o.x = (xa[0] - mean) * inv * s_prm[16 * 128 + l32 * 4 + 0] + s_prm[17 * 128 + l32 * 4 + 0];
    o.y = (xa[1] - mean) * inv * s_prm[16 * 128 + l32 * 4 + 1] + s_prm[17 * 128 + l32 * 4 + 1];
    o.z = (xa[2] - mean) * inv * s_prm[16 * 128 + l32 * 4 + 2] + s_prm[17 * 128 + l32 * 4 + 2];
    o.w = (xa[3] - mean) * inv * s_prm[16 * 128 + l32 * 4 + 3] + s_prm[17 * 128 + l32 * 4 + 3];
    *(float4*)&out[(size_t)(ebase + eo) * 128 + l32 * 4] = o;
  }
}

extern "C" void kernel_launch(void* const* d_in, const int* in_sizes, int n_in,
                              void* d_out, int out_size, void* d_ws, size_t ws_size,
                              hipStream_t stream) {
  const float* cur_x   = (const float*)d_in[0];
  const float* nb_x    = (const float*)d_in[1];
  const int*   nbm     = (const int*)d_in[2];
  const float* enc_w1  = (const float*)d_in[3];
  const float* enc_b1  = (const float*)d_in[4];
  const float* enc_g1  = (const float*)d_in[5];
  const float* enc_be1 = (const float*)d_in[6];
  const float* enc_w2  = (const float*)d_in[7];
  const float* enc_b2  = (const float*)d_in[8];
  const float* enc_g2  = (const float*)d_in[9];
  const float* enc_be2 = (const float*)d_in[10];
  const float* in_pw   = (const float*)d_in[11];
  const float* in_pb   = (const float*)d_in[12];
  const float* out_w   = (const float*)d_in[13];
  const float* out_b   = (const float*)d_in[14];
  const float* an_g    = (const float*)d_in[15];
  const float* an_b    = (const float*)d_in[16];
  const float* p1_w    = (const float*)d_in[17];
  const float* p1_b    = (const float*)d_in[18];
  const float* p1_g    = (const float*)d_in[19];
  const float* p1_be   = (const float*)d_in[20];
  const float* p2_w    = (const float*)d_in[21];
  const float* p2_b    = (const float*)d_in[22];
  const float* p2_g    = (const float*)d_in[23];
  const float* p2_be   = (const float*)d_in[24];
  float* out = (float*)d_out;

  unsigned short* wsb = (unsigned short*)d_ws;
  float* wsp = (float*)(wsb + WS_BF16_TOT);
  const int B = in_sizes[0] / 16;
  const bool split = (ws_size >= SPLIT_NEED) && (B == 32768);

  prep<<<128, 256, 0, stream>>>(enc_w1, enc_w2, in_pw, out_w, p1_w, p2_w,
                                enc_b1, enc_g1, enc_be1, enc_b2, enc_g2, enc_be2,
                                in_pb, out_b, an_g, an_b, p1_b, p1_g, p1_be,
                                p2_b, p2_g, p2_be, wsb, wsp, split ? 1 : 0);

  if (split) {
    k1_enc<<<1152, 512, 0, stream>>>(cur_x, nb_x, wsb, wsp, wsb);
    k2_head<<<B / 64, 256, 0, stream>>>(nbm, wsb, wsp, out);
  } else {
    gcn_mfma<<<B / TBE, NTH, 0, stream>>>(cur_x, nb_x, nbm, wsb, wsp, out);
  }
}